// Round 12
// baseline (1095.649 us; speedup 1.0000x reference)
//
#include <hip/hip_runtime.h>
#include <hip/hip_bf16.h>
#include <hip/hip_fp16.h>

#define BB 256
#define SS 32
#define II 128
#define HH 256
#define LBL 200
#define NSUBS 491
#define NATOMS_N 8000
#define NMOL_N 600

typedef const float* fp;

__device__ __forceinline__ float sigm(float x) { return 1.f / (1.f + expf(-x)); }
__device__ __forceinline__ float hlo(unsigned u) {
  return __half2float(__ushort_as_half((unsigned short)(u & 0xffffu)));
}
__device__ __forceinline__ float hhi(unsigned u) {
  return __half2float(__ushort_as_half((unsigned short)(u >> 16)));
}

// ---------------------------------------------------------------------------
// prep (134 blocks): idxv, mstart, masked w_masklin, and fp16-packed GRU
// weights wPh[(g*64+k4)*768 + gate*256 + j] = uint2 of 4 fp16 weights
// whh_g[gate*256+j][k4*4 .. k4*4+3].
// ---------------------------------------------------------------------------
__global__ __launch_bounds__(256) void prep_kernel(
    const int* __restrict__ mask, int* __restrict__ idxv,
    const int* __restrict__ seg, int* __restrict__ mstart,
    fp w_masklin, fp ddi, float* __restrict__ mw,
    fp whh_c, fp whh_p, uint2* __restrict__ wPh)
{
  int bx = blockIdx.x, tid = threadIdx.x;
  if (bx == 0) {                         // idx[b] = clamp(sum(mask[b,:]) - 1)
    int s = 0;
    const int* mrow = mask + tid * SS;
    for (int t = 0; t < SS; ++t) s += mrow[t];
    s -= 1;
    if (s < 0) s = 0;
    if (s > SS - 1) s = SS - 1;
    idxv[tid] = s;
  } else if (bx == 1) {                  // mstart[m] = lower_bound(seg, m)
    for (int m = tid; m <= NMOL_N; m += 256) {
      if (m == NMOL_N) { mstart[m] = NATOMS_N; continue; }
      int lo = 0, hi = NATOMS_N;
      while (lo < hi) {
        int mid = (lo + hi) >> 1;
        if (seg[mid] < m) lo = mid + 1; else hi = mid;
      }
      mstart[m] = lo;
    }
  } else if (bx < 6) {                   // mw[s][l] = w_masklin[s][l]*ddi[l][s]
    for (int o = (bx - 2) * 256 + tid; o < NSUBS * LBL; o += 4 * 256) {
      int s = o / LBL, l = o - s * LBL;
      mw[o] = w_masklin[o] * ddi[l * NSUBS + s];
    }
  } else {                               // weight pack: one (g, k4) per block
    int lin = bx - 6;                    // 0..127
    int g = lin >> 6;
    int k4 = lin & 63;
    fp whh = g ? whh_p : whh_c;
    uint2* dst = wPh + (size_t)(g * 64 + k4) * 768;
#pragma unroll
    for (int gate = 0; gate < 3; ++gate) {
      const float* src = whh + (size_t)(gate * 256 + tid) * HH + k4 * 4;
      unsigned s0 = __half_as_ushort(__float2half(src[0]));
      unsigned s1 = __half_as_ushort(__float2half(src[1]));
      unsigned s2 = __half_as_ushort(__float2half(src[2]));
      unsigned s3 = __half_as_ushort(__float2half(src[3]));
      uint2 u;
      u.x = s0 | (s1 << 16);
      u.y = s2 | (s3 << 16);
      dst[gate * 256 + tid] = u;
    }
  }
}

// ---------------------------------------------------------------------------
// xp = x @ w_ih.T + b_ih, fp32. xp[g][b*SS+t][768], 8192 rows per g.
// grid (24576, 2): 512 mtiles x 48 ntiles
// ---------------------------------------------------------------------------
__global__ __launch_bounds__(256) void xp_gemm(
    fp x_c, fp x_p, fp wih_c, fp wih_p, fp bih_c, fp bih_p,
    float* __restrict__ xp)
{
  int g = blockIdx.y;
  fp x = g ? x_p : x_c;
  fp wih = g ? wih_p : wih_c;
  fp bih = g ? bih_p : bih_c;
  float* xpo = xp + (size_t)g * 8192 * 768;

  int bx = blockIdx.x;
  int mt = bx / 48, nt = bx - mt * 48;
  int m0 = mt << 4, n0 = nt << 4;
  int tid = threadIdx.x;

  __shared__ float As[16][132];
  __shared__ float Ws[16][132];
  for (int i = tid; i < 2048; i += 256) {
    int r = i >> 7, k = i & 127;
    As[r][k] = x[(size_t)(m0 + r) * II + k];
    Ws[r][k] = wih[(size_t)(n0 + r) * II + k];
  }
  __syncthreads();

  int ni = tid & 15, mi = tid >> 4;
  float acc = 0.f;
#pragma unroll 8
  for (int k = 0; k < II; ++k) acc = fmaf(As[mi][k], Ws[ni][k], acc);
  xpo[(size_t)(m0 + mi) * 768 + n0 + ni] = acc + bih[n0 + ni];
}

// ---------------------------------------------------------------------------
// fully-fused MPNN: one block per molecule (<=14 atoms).
// ---------------------------------------------------------------------------
__global__ __launch_bounds__(256) void mpnn_mol(
    const int* __restrict__ fingerprints, fp embed_fp, fp adj,
    const int* __restrict__ mstart, fp w_g0, fp b_g0, fp w_g1, fp b_g1,
    float* __restrict__ mol)
{
  int m = blockIdx.x, tid = threadIdx.x;
  int a0 = mstart[m], a1 = mstart[m + 1];
  int sz = a1 - a0;
  if (sz < 0) sz = 0;
  if (sz > 14) sz = 14;

  __shared__ float v[14][260];
  __shared__ float adjb[14][16];

#pragma unroll
  for (int i = 0; i < 14; ++i) {
    float val = 0.f;
    if (i < sz) {
      int f = fingerprints[a0 + i] & 1023;
      val = embed_fp[(size_t)f * HH + tid];
    }
    v[i][tid] = val;
  }
  if (tid < 224) {
    int i = tid >> 4, jj = tid & 15;
    float a = 0.f;
    if (i < sz && jj < sz)
      a = adj[(size_t)(a0 + i) * NATOMS_N + a0 + jj];
    adjb[i][jj] = a;
  }
  __syncthreads();

  float acc[14];
  for (int rd = 0; rd < 2; ++rd) {
    const float* wp0 = (rd ? w_g1 : w_g0) + tid;
#pragma unroll
    for (int i = 0; i < 14; ++i) acc[i] = 0.f;
    for (int k = 0; k < HH; k += 4) {
      float w0 = wp0[(size_t)k * HH];
      float w1 = wp0[(size_t)(k + 1) * HH];
      float w2 = wp0[(size_t)(k + 2) * HH];
      float w3 = wp0[(size_t)(k + 3) * HH];
#pragma unroll
      for (int i = 0; i < 14; ++i) {
        float4 vv = *(const float4*)&v[i][k];
        acc[i] = fmaf(vv.x, w0, acc[i]);
        acc[i] = fmaf(vv.y, w1, acc[i]);
        acc[i] = fmaf(vv.z, w2, acc[i]);
        acc[i] = fmaf(vv.w, w3, acc[i]);
      }
    }
    float bias = (rd ? b_g1 : b_g0)[tid];
    float hreg[14];
#pragma unroll
    for (int i = 0; i < 14; ++i) hreg[i] = fmaxf(acc[i] + bias, 0.f);
#pragma unroll
    for (int i = 0; i < 14; ++i) {
      float s = hreg[i];
#pragma unroll
      for (int jj = 0; jj < 14; ++jj) s = fmaf(adjb[i][jj], hreg[jj], s);
      acc[i] = s;
    }
    if (rd == 0) {
      __syncthreads();
#pragma unroll
      for (int i = 0; i < 14; ++i) v[i][tid] = acc[i];
      __syncthreads();
    }
  }
  float msum = 0.f;
#pragma unroll
  for (int i = 0; i < 14; ++i) if (i < sz) msum += acc[i];
  mol[(size_t)m * HH + tid] = msum;
}

// ---------------------------------------------------------------------------
// mpnn_emb^T[h][d] = sum_m avg[d][m] * mol[m][h]
// ---------------------------------------------------------------------------
__global__ __launch_bounds__(256) void mpnn_emb_k(
    fp avg, const float* __restrict__ mol, float* __restrict__ embT)
{
  int d = blockIdx.x, tid = threadIdx.x;
  float acc = 0.f;
  for (int m = 0; m < NMOL_N; ++m)
    acc += avg[d * NMOL_N + m] * mol[(size_t)m * HH + tid];
  embT[(size_t)tid * LBL + d] = acc;
}

// ---------------------------------------------------------------------------
// GRU, one batch per block: 512 blocks = g(2) x b(256) -> 2 blocks/CU,
// 2 waves/SIMD so L2 weight-load latency is hidden by the co-resident wave
// (round 11 at 1 wave/SIMD stalled 45% on waitcnt). h block-local in LDS
// across all 32 steps; fp16-packed weights streamed from XCD-L2.
// ---------------------------------------------------------------------------
__global__ __launch_bounds__(256) void gru_local1b(
    fp xp, const uint2* __restrict__ wPh, fp bhh_c, fp bhh_p,
    float* __restrict__ hcat, const int* __restrict__ idxv)
{
  int blk = blockIdx.x;
  int g = blk >> 8;
  int b = blk & 255;
  int tid = threadIdx.x;               // = j
  const uint2* wg = wPh + (size_t)g * 64 * 768 + tid;
  fp bhh = g ? bhh_p : bhh_c;
  const float* xpb = xp + ((size_t)g * 8192 + (size_t)b * SS) * 768;

  __shared__ float hs[260];
  hs[tid] = 0.f;
  float br = bhh[tid], bz = bhh[tid + 256], bn = bhh[tid + 512];
  int id = idxv[b];
  __syncthreads();

  for (int t = 0; t < SS; ++t) {
    float sr = 0.f, sz = 0.f, sn = 0.f;
#pragma unroll 4
    for (int k4 = 0; k4 < 64; ++k4) {
      float4 a = *(const float4*)&hs[k4 * 4];
      const uint2* base = wg + (size_t)k4 * 768;
      uint2 u0 = base[0];              // gate r, 4 fp16
      uint2 u1 = base[256];            // gate z
      uint2 u2 = base[512];            // gate n
      sr = fmaf(a.x, hlo(u0.x), sr); sr = fmaf(a.y, hhi(u0.x), sr);
      sr = fmaf(a.z, hlo(u0.y), sr); sr = fmaf(a.w, hhi(u0.y), sr);
      sz = fmaf(a.x, hlo(u1.x), sz); sz = fmaf(a.y, hhi(u1.x), sz);
      sz = fmaf(a.z, hlo(u1.y), sz); sz = fmaf(a.w, hhi(u1.y), sz);
      sn = fmaf(a.x, hlo(u2.x), sn); sn = fmaf(a.y, hhi(u2.x), sn);
      sn = fmaf(a.z, hlo(u2.y), sn); sn = fmaf(a.w, hhi(u2.y), sn);
    }
    const float* xrow = xpb + (size_t)t * 768;
    float r = sigm(xrow[tid] + sr + br);
    float z = sigm(xrow[tid + 256] + sz + bz);
    float n = tanhf(xrow[tid + 512] + r * (sn + bn));
    float hnew = (1.f - z) * n + z * hs[tid];
    __syncthreads();                   // all h reads of this step done
    hs[tid] = hnew;
    if (t == id) hcat[(size_t)b * 512 + g * 256 + tid] = fmaxf(hnew, 0.f);
    __syncthreads();
  }
}

// ---------------------------------------------------------------------------
// fp32 GEMM for query: C[M,N] = A[M,K] @ W[K,N] + bias
// ---------------------------------------------------------------------------
__global__ __launch_bounds__(256) void gemm_f32(
    const float* __restrict__ A, fp W, fp bias, float* __restrict__ C,
    int M, int N, int K)
{
  int ntiles = N >> 4;
  int mt = blockIdx.x / ntiles, nt = blockIdx.x - mt * ntiles;
  int m0 = mt << 4, n0 = nt << 4;
  int tid = threadIdx.x;
  int ni = tid & 15, mi = tid >> 4;
  __shared__ float As[16][68];
  float acc = 0.f;
  for (int k0 = 0; k0 < K; k0 += 64) {
    __syncthreads();
    for (int i = tid; i < 1024; i += 256) {
      int r = i >> 6, kk = i & 63;
      As[r][kk] = A[(size_t)(m0 + r) * K + k0 + kk];
    }
    __syncthreads();
    const float* wp = W + (size_t)k0 * N + n0 + ni;
#pragma unroll 4
    for (int kk = 0; kk < 64; ++kk)
      acc = fmaf(As[mi][kk], wp[(size_t)kk * N], acc);
  }
  acc += bias[n0 + ni];
  C[(size_t)(m0 + mi) * N + n0 + ni] = acc;
}

// ---------------------------------------------------------------------------
// fused tail per batch row: match/x2/LN (mpnn_att) + bip/masked-linear + mul
// ---------------------------------------------------------------------------
__global__ __launch_bounds__(256) void tail_fused(
    const float* __restrict__ query, const float* __restrict__ embT,
    fp w_out, fp b_out, fp gamma, fp beta,
    fp w_bip, fp b_bip, const float* __restrict__ mw,
    float* __restrict__ out)
{
  int b = blockIdx.x, tid = threadIdx.x;
  __shared__ float q[HH];
  __shared__ float mrow[LBL];
  __shared__ float bips[NSUBS];
  __shared__ float red[256];
  q[tid] = query[(size_t)b * HH + tid];
  __syncthreads();
  if (tid < LBL) {
    float acc = 0.f;
    for (int k = 0; k < HH; ++k) acc += q[k] * embT[(size_t)k * LBL + tid];
    mrow[tid] = sigm(acc);
  }
  for (int s = tid; s < NSUBS; s += 256) {
    float acc = b_bip[s];
    for (int k = 0; k < HH; ++k) acc += q[k] * w_bip[(size_t)k * NSUBS + s];
    bips[s] = acc;
  }
  __syncthreads();
  float x2 = 0.f;
  if (tid < LBL) {
    float acc = b_out[tid] + mrow[tid];
    for (int jj = 0; jj < LBL; ++jj) acc += mrow[jj] * w_out[jj * LBL + tid];
    x2 = acc;
  }
  red[tid] = (tid < LBL) ? x2 : 0.f;
  __syncthreads();
  for (int s = 128; s > 0; s >>= 1) {
    if (tid < s) red[tid] += red[tid + s];
    __syncthreads();
  }
  float mu = red[0] / (float)LBL;
  __syncthreads();
  float dv = (tid < LBL) ? (x2 - mu) : 0.f;
  red[tid] = dv * dv;
  __syncthreads();
  for (int s = 128; s > 0; s >>= 1) {
    if (tid < s) red[tid] += red[tid + s];
    __syncthreads();
  }
  float var = red[0] / (float)LBL;
  if (tid < LBL) {
    float matt = (x2 - mu) * rsqrtf(var + 1e-5f) * gamma[tid] + beta[tid];
    float acc = 0.f;
    for (int s = 0; s < NSUBS; ++s) acc += bips[s] * mw[(size_t)s * LBL + tid];
    out[(size_t)b * LBL + tid] = acc * matt;
  }
}

// ---------------------------------------------------------------------------
extern "C" void kernel_launch(void* const* d_in, const int* in_sizes, int n_in,
                              void* d_out, int out_size, void* d_ws, size_t ws_size,
                              hipStream_t stream)
{
  fp x_c   = (fp)d_in[0];
  fp x_p   = (fp)d_in[1];
  const int* mask = (const int*)d_in[2];
  fp wih_c = (fp)d_in[3];
  fp whh_c = (fp)d_in[4];
  fp bih_c = (fp)d_in[5];
  fp bhh_c = (fp)d_in[6];
  fp wih_p = (fp)d_in[7];
  fp whh_p = (fp)d_in[8];
  fp bih_p = (fp)d_in[9];
  fp bhh_p = (fp)d_in[10];
  fp w_query = (fp)d_in[11];
  fp b_query = (fp)d_in[12];
  fp w_bip = (fp)d_in[13];
  fp b_bip = (fp)d_in[14];
  fp w_masklin = (fp)d_in[15];
  fp ddi = (fp)d_in[16];
  fp embed_fp = (fp)d_in[17];
  const int* fingerprints = (const int*)d_in[18];
  fp adj = (fp)d_in[19];
  const int* seg = (const int*)d_in[20];
  fp w_g0 = (fp)d_in[21];
  fp b_g0 = (fp)d_in[22];
  fp w_g1 = (fp)d_in[23];
  fp b_g1 = (fp)d_in[24];
  fp avg = (fp)d_in[25];
  fp w_out = (fp)d_in[26];
  fp b_out = (fp)d_in[27];
  fp gamma = (fp)d_in[28];
  fp beta = (fp)d_in[29];
  float* out = (float*)d_out;

  char* w = (char*)d_ws;
  size_t off = 0;
  auto alloc = [&](size_t bytes) -> void* {
    void* p = w + off;
    off = (off + bytes + 255) & ~(size_t)255;
    return p;
  };

  float* xp   = (float*)alloc((size_t)2 * 8192 * 768 * 4);   // 50.3 MB
  uint2* wPh  = (uint2*)alloc((size_t)2 * 64 * 768 * 8);     // 786 KB
  float* mol  = (float*)alloc((size_t)NMOL_N * HH * 4);
  float* embT = (float*)alloc((size_t)HH * LBL * 4);
  float* hcat = (float*)alloc((size_t)BB * 2 * HH * 4);
  float* query = (float*)alloc((size_t)BB * HH * 4);
  float* mw   = (float*)alloc((size_t)NSUBS * LBL * 4);
  int* idxv   = (int*)alloc(256 * 4);
  int* mstart = (int*)alloc((NMOL_N + 1) * 4);

  prep_kernel<<<134, 256, 0, stream>>>(mask, idxv, seg, mstart, w_masklin, ddi,
                                       mw, whh_c, whh_p, wPh);

  xp_gemm<<<dim3(24576, 2), 256, 0, stream>>>(x_c, x_p, wih_c, wih_p,
                                              bih_c, bih_p, xp);

  mpnn_mol<<<NMOL_N, 256, 0, stream>>>(fingerprints, embed_fp, adj, mstart,
                                       w_g0, b_g0, w_g1, b_g1, mol);
  mpnn_emb_k<<<LBL, 256, 0, stream>>>(avg, mol, embT);

  gru_local1b<<<512, 256, 0, stream>>>(xp, wPh, bhh_c, bhh_p, hcat, idxv);

  gemm_f32<<<256, 256, 0, stream>>>(hcat, w_query, b_query, query, BB, HH, 2 * HH);
  tail_fused<<<BB, 256, 0, stream>>>(query, embT, w_out, b_out, gamma, beta,
                                     w_bip, b_bip, mw, out);
}

// Round 13
// 973.351 us; speedup vs baseline: 1.1256x; 1.1256x over previous
//
#include <hip/hip_runtime.h>
#include <hip/hip_bf16.h>
#include <hip/hip_fp16.h>

#define BB 256
#define SS 32
#define II 128
#define HH 256
#define LBL 200
#define NSUBS 491
#define NATOMS_N 8000
#define NMOL_N 600

typedef const float* fp;

__device__ __forceinline__ float sigm(float x) { return 1.f / (1.f + expf(-x)); }
__device__ __forceinline__ float hlo(unsigned u) {
  return __half2float(__ushort_as_half((unsigned short)(u & 0xffffu)));
}
__device__ __forceinline__ float hhi(unsigned u) {
  return __half2float(__ushort_as_half((unsigned short)(u >> 16)));
}

// ---------------------------------------------------------------------------
// prep (70 blocks): idxv, mstart, masked w_masklin, and fp16 uint4-packed GRU
// weights wQ[(g*32+kk8)*768 + gate*256 + j] = uint4 of 8 fp16 =
// whh_g[gate*256+j][kk8*8 .. kk8*8+7]. 16B/lane loads in the GRU kernel.
// ---------------------------------------------------------------------------
__global__ __launch_bounds__(256) void prep_kernel(
    const int* __restrict__ mask, int* __restrict__ idxv,
    const int* __restrict__ seg, int* __restrict__ mstart,
    fp w_masklin, fp ddi, float* __restrict__ mw,
    fp whh_c, fp whh_p, uint4* __restrict__ wQ)
{
  int bx = blockIdx.x, tid = threadIdx.x;
  if (bx == 0) {                         // idx[b] = clamp(sum(mask[b,:]) - 1)
    int s = 0;
    const int* mrow = mask + tid * SS;
    for (int t = 0; t < SS; ++t) s += mrow[t];
    s -= 1;
    if (s < 0) s = 0;
    if (s > SS - 1) s = SS - 1;
    idxv[tid] = s;
  } else if (bx == 1) {                  // mstart[m] = lower_bound(seg, m)
    for (int m = tid; m <= NMOL_N; m += 256) {
      if (m == NMOL_N) { mstart[m] = NATOMS_N; continue; }
      int lo = 0, hi = NATOMS_N;
      while (lo < hi) {
        int mid = (lo + hi) >> 1;
        if (seg[mid] < m) lo = mid + 1; else hi = mid;
      }
      mstart[m] = lo;
    }
  } else if (bx < 6) {                   // mw[s][l] = w_masklin[s][l]*ddi[l][s]
    for (int o = (bx - 2) * 256 + tid; o < NSUBS * LBL; o += 4 * 256) {
      int s = o / LBL, l = o - s * LBL;
      mw[o] = w_masklin[o] * ddi[l * NSUBS + s];
    }
  } else {                               // weight pack: one (g, kk8) per block
    int lin = bx - 6;                    // 0..63
    int g = lin >> 5;
    int kk8 = lin & 31;
    fp whh = g ? whh_p : whh_c;
    uint4* dst = wQ + (size_t)(g * 32 + kk8) * 768;
#pragma unroll
    for (int gate = 0; gate < 3; ++gate) {
      const float* src = whh + (size_t)(gate * 256 + tid) * HH + kk8 * 8;
      unsigned v0 = __half_as_ushort(__float2half(src[0]));
      unsigned v1 = __half_as_ushort(__float2half(src[1]));
      unsigned v2 = __half_as_ushort(__float2half(src[2]));
      unsigned v3 = __half_as_ushort(__float2half(src[3]));
      unsigned v4 = __half_as_ushort(__float2half(src[4]));
      unsigned v5 = __half_as_ushort(__float2half(src[5]));
      unsigned v6 = __half_as_ushort(__float2half(src[6]));
      unsigned v7 = __half_as_ushort(__float2half(src[7]));
      uint4 u;
      u.x = v0 | (v1 << 16);
      u.y = v2 | (v3 << 16);
      u.z = v4 | (v5 << 16);
      u.w = v6 | (v7 << 16);
      dst[gate * 256 + tid] = u;
    }
  }
}

// ---------------------------------------------------------------------------
// xp = x @ w_ih.T + b_ih, fp32. xp[g][b*SS+t][768], 8192 rows per g.
// grid (24576, 2): 512 mtiles x 48 ntiles
// ---------------------------------------------------------------------------
__global__ __launch_bounds__(256) void xp_gemm(
    fp x_c, fp x_p, fp wih_c, fp wih_p, fp bih_c, fp bih_p,
    float* __restrict__ xp)
{
  int g = blockIdx.y;
  fp x = g ? x_p : x_c;
  fp wih = g ? wih_p : wih_c;
  fp bih = g ? bih_p : bih_c;
  float* xpo = xp + (size_t)g * 8192 * 768;

  int bx = blockIdx.x;
  int mt = bx / 48, nt = bx - mt * 48;
  int m0 = mt << 4, n0 = nt << 4;
  int tid = threadIdx.x;

  __shared__ float As[16][132];
  __shared__ float Ws[16][132];
  for (int i = tid; i < 2048; i += 256) {
    int r = i >> 7, k = i & 127;
    As[r][k] = x[(size_t)(m0 + r) * II + k];
    Ws[r][k] = wih[(size_t)(n0 + r) * II + k];
  }
  __syncthreads();

  int ni = tid & 15, mi = tid >> 4;
  float acc = 0.f;
#pragma unroll 8
  for (int k = 0; k < II; ++k) acc = fmaf(As[mi][k], Ws[ni][k], acc);
  xpo[(size_t)(m0 + mi) * 768 + n0 + ni] = acc + bih[n0 + ni];
}

// ---------------------------------------------------------------------------
// fully-fused MPNN: one block per molecule (<=14 atoms).
// ---------------------------------------------------------------------------
__global__ __launch_bounds__(256) void mpnn_mol(
    const int* __restrict__ fingerprints, fp embed_fp, fp adj,
    const int* __restrict__ mstart, fp w_g0, fp b_g0, fp w_g1, fp b_g1,
    float* __restrict__ mol)
{
  int m = blockIdx.x, tid = threadIdx.x;
  int a0 = mstart[m], a1 = mstart[m + 1];
  int sz = a1 - a0;
  if (sz < 0) sz = 0;
  if (sz > 14) sz = 14;

  __shared__ float v[14][260];
  __shared__ float adjb[14][16];

#pragma unroll
  for (int i = 0; i < 14; ++i) {
    float val = 0.f;
    if (i < sz) {
      int f = fingerprints[a0 + i] & 1023;
      val = embed_fp[(size_t)f * HH + tid];
    }
    v[i][tid] = val;
  }
  if (tid < 224) {
    int i = tid >> 4, jj = tid & 15;
    float a = 0.f;
    if (i < sz && jj < sz)
      a = adj[(size_t)(a0 + i) * NATOMS_N + a0 + jj];
    adjb[i][jj] = a;
  }
  __syncthreads();

  float acc[14];
  for (int rd = 0; rd < 2; ++rd) {
    const float* wp0 = (rd ? w_g1 : w_g0) + tid;
#pragma unroll
    for (int i = 0; i < 14; ++i) acc[i] = 0.f;
    for (int k = 0; k < HH; k += 4) {
      float w0 = wp0[(size_t)k * HH];
      float w1 = wp0[(size_t)(k + 1) * HH];
      float w2 = wp0[(size_t)(k + 2) * HH];
      float w3 = wp0[(size_t)(k + 3) * HH];
#pragma unroll
      for (int i = 0; i < 14; ++i) {
        float4 vv = *(const float4*)&v[i][k];
        acc[i] = fmaf(vv.x, w0, acc[i]);
        acc[i] = fmaf(vv.y, w1, acc[i]);
        acc[i] = fmaf(vv.z, w2, acc[i]);
        acc[i] = fmaf(vv.w, w3, acc[i]);
      }
    }
    float bias = (rd ? b_g1 : b_g0)[tid];
    float hreg[14];
#pragma unroll
    for (int i = 0; i < 14; ++i) hreg[i] = fmaxf(acc[i] + bias, 0.f);
#pragma unroll
    for (int i = 0; i < 14; ++i) {
      float s = hreg[i];
#pragma unroll
      for (int jj = 0; jj < 14; ++jj) s = fmaf(adjb[i][jj], hreg[jj], s);
      acc[i] = s;
    }
    if (rd == 0) {
      __syncthreads();
#pragma unroll
      for (int i = 0; i < 14; ++i) v[i][tid] = acc[i];
      __syncthreads();
    }
  }
  float msum = 0.f;
#pragma unroll
  for (int i = 0; i < 14; ++i) if (i < sz) msum += acc[i];
  mol[(size_t)m * HH + tid] = msum;
}

// ---------------------------------------------------------------------------
// mpnn_emb^T[h][d] = sum_m avg[d][m] * mol[m][h]
// ---------------------------------------------------------------------------
__global__ __launch_bounds__(256) void mpnn_emb_k(
    fp avg, const float* __restrict__ mol, float* __restrict__ embT)
{
  int d = blockIdx.x, tid = threadIdx.x;
  float acc = 0.f;
  for (int m = 0; m < NMOL_N; ++m)
    acc += avg[d * NMOL_N + m] * mol[(size_t)m * HH + tid];
  embT[(size_t)tid * LBL + d] = acc;
}

// ---------------------------------------------------------------------------
// GRU v4, k-split: 256 blocks (g x 128 pairs) x 512 threads. Thread (j, kh)
// handles k-half kh*128..+127 for BOTH batches -> per-CU load count equals
// r11 (every weight loaded once/CU/step) but 8 waves/CU (2/SIMD) hide L2
// latency, and uint4 loads (8 fp16) halve load instructions. Partial sums
// combine via LDS; gate phase: thread (kh=batch, j).
// ---------------------------------------------------------------------------
__global__ __launch_bounds__(512) void gru_ks(
    fp xp, const uint4* __restrict__ wQ, fp bhh_c, fp bhh_p,
    float* __restrict__ hcat, const int* __restrict__ idxv)
{
  int blk = blockIdx.x;
  int g = blk >> 7;
  int pair = blk & 127;
  int b1 = pair * 2, b2 = b1 + 1;
  int tid = threadIdx.x;
  int j = tid & 255;
  int kh = tid >> 8;                   // k-half 0/1

  __shared__ float hs[2][260];         // [batch][k]
  __shared__ float red[12][260];       // [kh*6 + batch*3 + gate][j]

  const uint4* wg = wQ + (size_t)(g * 32 + kh * 16) * 768 + j;
  fp bhh = g ? bhh_p : bhh_c;
  const float* xpg = xp + (size_t)g * 8192 * 768;

  if (kh == 0) { hs[0][j] = 0.f; hs[1][j] = 0.f; }
  float br = bhh[j], bz = bhh[j + 256], bn = bhh[j + 512];
  int myb = kh ? b2 : b1;
  int myid = idxv[myb];
  __syncthreads();

  for (int t = 0; t < SS; ++t) {
    const float* h1p = &hs[0][kh * 128];
    const float* h2p = &hs[1][kh * 128];
    float s1r = 0.f, s1z = 0.f, s1n = 0.f;
    float s2r = 0.f, s2z = 0.f, s2n = 0.f;
#pragma unroll 4
    for (int i = 0; i < 16; ++i) {
      float4 a1a = *(const float4*)(h1p + i * 8);
      float4 a1b = *(const float4*)(h1p + i * 8 + 4);
      float4 a2a = *(const float4*)(h2p + i * 8);
      float4 a2b = *(const float4*)(h2p + i * 8 + 4);
      const uint4* base = wg + (size_t)i * 768;
      uint4 ur = base[0];
      uint4 uz = base[256];
      uint4 un = base[512];
      // gate r
      {
        float w0 = hlo(ur.x), w1 = hhi(ur.x), w2 = hlo(ur.y), w3 = hhi(ur.y);
        float w4 = hlo(ur.z), w5 = hhi(ur.z), w6 = hlo(ur.w), w7 = hhi(ur.w);
        s1r = fmaf(a1a.x, w0, s1r); s1r = fmaf(a1a.y, w1, s1r);
        s1r = fmaf(a1a.z, w2, s1r); s1r = fmaf(a1a.w, w3, s1r);
        s1r = fmaf(a1b.x, w4, s1r); s1r = fmaf(a1b.y, w5, s1r);
        s1r = fmaf(a1b.z, w6, s1r); s1r = fmaf(a1b.w, w7, s1r);
        s2r = fmaf(a2a.x, w0, s2r); s2r = fmaf(a2a.y, w1, s2r);
        s2r = fmaf(a2a.z, w2, s2r); s2r = fmaf(a2a.w, w3, s2r);
        s2r = fmaf(a2b.x, w4, s2r); s2r = fmaf(a2b.y, w5, s2r);
        s2r = fmaf(a2b.z, w6, s2r); s2r = fmaf(a2b.w, w7, s2r);
      }
      // gate z
      {
        float w0 = hlo(uz.x), w1 = hhi(uz.x), w2 = hlo(uz.y), w3 = hhi(uz.y);
        float w4 = hlo(uz.z), w5 = hhi(uz.z), w6 = hlo(uz.w), w7 = hhi(uz.w);
        s1z = fmaf(a1a.x, w0, s1z); s1z = fmaf(a1a.y, w1, s1z);
        s1z = fmaf(a1a.z, w2, s1z); s1z = fmaf(a1a.w, w3, s1z);
        s1z = fmaf(a1b.x, w4, s1z); s1z = fmaf(a1b.y, w5, s1z);
        s1z = fmaf(a1b.z, w6, s1z); s1z = fmaf(a1b.w, w7, s1z);
        s2z = fmaf(a2a.x, w0, s2z); s2z = fmaf(a2a.y, w1, s2z);
        s2z = fmaf(a2a.z, w2, s2z); s2z = fmaf(a2a.w, w3, s2z);
        s2z = fmaf(a2b.x, w4, s2z); s2z = fmaf(a2b.y, w5, s2z);
        s2z = fmaf(a2b.z, w6, s2z); s2z = fmaf(a2b.w, w7, s2z);
      }
      // gate n
      {
        float w0 = hlo(un.x), w1 = hhi(un.x), w2 = hlo(un.y), w3 = hhi(un.y);
        float w4 = hlo(un.z), w5 = hhi(un.z), w6 = hlo(un.w), w7 = hhi(un.w);
        s1n = fmaf(a1a.x, w0, s1n); s1n = fmaf(a1a.y, w1, s1n);
        s1n = fmaf(a1a.z, w2, s1n); s1n = fmaf(a1a.w, w3, s1n);
        s1n = fmaf(a1b.x, w4, s1n); s1n = fmaf(a1b.y, w5, s1n);
        s1n = fmaf(a1b.z, w6, s1n); s1n = fmaf(a1b.w, w7, s1n);
        s2n = fmaf(a2a.x, w0, s2n); s2n = fmaf(a2a.y, w1, s2n);
        s2n = fmaf(a2a.z, w2, s2n); s2n = fmaf(a2a.w, w3, s2n);
        s2n = fmaf(a2b.x, w4, s2n); s2n = fmaf(a2b.y, w5, s2n);
        s2n = fmaf(a2b.z, w6, s2n); s2n = fmaf(a2b.w, w7, s2n);
      }
    }
    int rb = kh * 6;
    red[rb + 0][j] = s1r; red[rb + 1][j] = s1z; red[rb + 2][j] = s1n;
    red[rb + 3][j] = s2r; red[rb + 4][j] = s2z; red[rb + 5][j] = s2n;
    __syncthreads();                   // partials visible; all hs reads done

    // gate phase: thread (kh = batch-in-pair, j); writes only its own hs slot
    {
      int bb = kh * 3;
      float sr = red[bb + 0][j] + red[6 + bb + 0][j];
      float sz = red[bb + 1][j] + red[6 + bb + 1][j];
      float sn = red[bb + 2][j] + red[6 + bb + 2][j];
      const float* xrow = xpg + ((size_t)myb * SS + t) * 768;
      float r = sigm(xrow[j] + sr + br);
      float z = sigm(xrow[j + 256] + sz + bz);
      float n = tanhf(xrow[j + 512] + r * (sn + bn));
      float hnew = (1.f - z) * n + z * hs[kh][j];
      hs[kh][j] = hnew;
      if (t == myid) hcat[(size_t)myb * 512 + g * 256 + j] = fmaxf(hnew, 0.f);
    }
    __syncthreads();                   // hs update visible before next step
  }
}

// ---------------------------------------------------------------------------
// fp32 GEMM for query: C[M,N] = A[M,K] @ W[K,N] + bias
// ---------------------------------------------------------------------------
__global__ __launch_bounds__(256) void gemm_f32(
    const float* __restrict__ A, fp W, fp bias, float* __restrict__ C,
    int M, int N, int K)
{
  int ntiles = N >> 4;
  int mt = blockIdx.x / ntiles, nt = blockIdx.x - mt * ntiles;
  int m0 = mt << 4, n0 = nt << 4;
  int tid = threadIdx.x;
  int ni = tid & 15, mi = tid >> 4;
  __shared__ float As[16][68];
  float acc = 0.f;
  for (int k0 = 0; k0 < K; k0 += 64) {
    __syncthreads();
    for (int i = tid; i < 1024; i += 256) {
      int r = i >> 6, kk = i & 63;
      As[r][kk] = A[(size_t)(m0 + r) * K + k0 + kk];
    }
    __syncthreads();
    const float* wp = W + (size_t)k0 * N + n0 + ni;
#pragma unroll 4
    for (int kk = 0; kk < 64; ++kk)
      acc = fmaf(As[mi][kk], wp[(size_t)kk * N], acc);
  }
  acc += bias[n0 + ni];
  C[(size_t)(m0 + mi) * N + n0 + ni] = acc;
}

// ---------------------------------------------------------------------------
// fused tail per batch row: match/x2/LN (mpnn_att) + bip/masked-linear + mul
// ---------------------------------------------------------------------------
__global__ __launch_bounds__(256) void tail_fused(
    const float* __restrict__ query, const float* __restrict__ embT,
    fp w_out, fp b_out, fp gamma, fp beta,
    fp w_bip, fp b_bip, const float* __restrict__ mw,
    float* __restrict__ out)
{
  int b = blockIdx.x, tid = threadIdx.x;
  __shared__ float q[HH];
  __shared__ float mrow[LBL];
  __shared__ float bips[NSUBS];
  __shared__ float red[256];
  q[tid] = query[(size_t)b * HH + tid];
  __syncthreads();
  if (tid < LBL) {
    float acc = 0.f;
    for (int k = 0; k < HH; ++k) acc += q[k] * embT[(size_t)k * LBL + tid];
    mrow[tid] = sigm(acc);
  }
  for (int s = tid; s < NSUBS; s += 256) {
    float acc = b_bip[s];
    for (int k = 0; k < HH; ++k) acc += q[k] * w_bip[(size_t)k * NSUBS + s];
    bips[s] = acc;
  }
  __syncthreads();
  float x2 = 0.f;
  if (tid < LBL) {
    float acc = b_out[tid] + mrow[tid];
    for (int jj = 0; jj < LBL; ++jj) acc += mrow[jj] * w_out[jj * LBL + tid];
    x2 = acc;
  }
  red[tid] = (tid < LBL) ? x2 : 0.f;
  __syncthreads();
  for (int s = 128; s > 0; s >>= 1) {
    if (tid < s) red[tid] += red[tid + s];
    __syncthreads();
  }
  float mu = red[0] / (float)LBL;
  __syncthreads();
  float dv = (tid < LBL) ? (x2 - mu) : 0.f;
  red[tid] = dv * dv;
  __syncthreads();
  for (int s = 128; s > 0; s >>= 1) {
    if (tid < s) red[tid] += red[tid + s];
    __syncthreads();
  }
  float var = red[0] / (float)LBL;
  if (tid < LBL) {
    float matt = (x2 - mu) * rsqrtf(var + 1e-5f) * gamma[tid] + beta[tid];
    float acc = 0.f;
    for (int s = 0; s < NSUBS; ++s) acc += bips[s] * mw[(size_t)s * LBL + tid];
    out[(size_t)b * LBL + tid] = acc * matt;
  }
}

// ---------------------------------------------------------------------------
extern "C" void kernel_launch(void* const* d_in, const int* in_sizes, int n_in,
                              void* d_out, int out_size, void* d_ws, size_t ws_size,
                              hipStream_t stream)
{
  fp x_c   = (fp)d_in[0];
  fp x_p   = (fp)d_in[1];
  const int* mask = (const int*)d_in[2];
  fp wih_c = (fp)d_in[3];
  fp whh_c = (fp)d_in[4];
  fp bih_c = (fp)d_in[5];
  fp bhh_c = (fp)d_in[6];
  fp wih_p = (fp)d_in[7];
  fp whh_p = (fp)d_in[8];
  fp bih_p = (fp)d_in[9];
  fp bhh_p = (fp)d_in[10];
  fp w_query = (fp)d_in[11];
  fp b_query = (fp)d_in[12];
  fp w_bip = (fp)d_in[13];
  fp b_bip = (fp)d_in[14];
  fp w_masklin = (fp)d_in[15];
  fp ddi = (fp)d_in[16];
  fp embed_fp = (fp)d_in[17];
  const int* fingerprints = (const int*)d_in[18];
  fp adj = (fp)d_in[19];
  const int* seg = (const int*)d_in[20];
  fp w_g0 = (fp)d_in[21];
  fp b_g0 = (fp)d_in[22];
  fp w_g1 = (fp)d_in[23];
  fp b_g1 = (fp)d_in[24];
  fp avg = (fp)d_in[25];
  fp w_out = (fp)d_in[26];
  fp b_out = (fp)d_in[27];
  fp gamma = (fp)d_in[28];
  fp beta = (fp)d_in[29];
  float* out = (float*)d_out;

  char* w = (char*)d_ws;
  size_t off = 0;
  auto alloc = [&](size_t bytes) -> void* {
    void* p = w + off;
    off = (off + bytes + 255) & ~(size_t)255;
    return p;
  };

  float* xp   = (float*)alloc((size_t)2 * 8192 * 768 * 4);   // 50.3 MB
  uint4* wQ   = (uint4*)alloc((size_t)2 * 32 * 768 * 16);    // 786 KB
  float* mol  = (float*)alloc((size_t)NMOL_N * HH * 4);
  float* embT = (float*)alloc((size_t)HH * LBL * 4);
  float* hcat = (float*)alloc((size_t)BB * 2 * HH * 4);
  float* query = (float*)alloc((size_t)BB * HH * 4);
  float* mw   = (float*)alloc((size_t)NSUBS * LBL * 4);
  int* idxv   = (int*)alloc(256 * 4);
  int* mstart = (int*)alloc((NMOL_N + 1) * 4);

  prep_kernel<<<70, 256, 0, stream>>>(mask, idxv, seg, mstart, w_masklin, ddi,
                                      mw, whh_c, whh_p, wQ);

  xp_gemm<<<dim3(24576, 2), 256, 0, stream>>>(x_c, x_p, wih_c, wih_p,
                                              bih_c, bih_p, xp);

  mpnn_mol<<<NMOL_N, 256, 0, stream>>>(fingerprints, embed_fp, adj, mstart,
                                       w_g0, b_g0, w_g1, b_g1, mol);
  mpnn_emb_k<<<LBL, 256, 0, stream>>>(avg, mol, embT);

  gru_ks<<<256, 512, 0, stream>>>(xp, wQ, bhh_c, bhh_p, hcat, idxv);

  gemm_f32<<<256, 256, 0, stream>>>(hcat, w_query, b_query, query, BB, HH, 2 * HH);
  tail_fused<<<BB, 256, 0, stream>>>(query, embT, w_out, b_out, gamma, beta,
                                     w_bip, b_bip, mw, out);
}

// Round 15
// 913.072 us; speedup vs baseline: 1.2000x; 1.0660x over previous
//
#include <hip/hip_runtime.h>
#include <hip/hip_bf16.h>
#include <hip/hip_fp16.h>

#define BB 256
#define SS 32
#define II 128
#define HH 256
#define LBL 200
#define NSUBS 491
#define NATOMS_N 8000
#define NMOL_N 600

typedef const float* fp;
typedef __attribute__((ext_vector_type(8))) _Float16 f16x8;
typedef __attribute__((ext_vector_type(4))) float f32x4;

__device__ __forceinline__ float sigm(float x) { return 1.f / (1.f + expf(-x)); }
__device__ __forceinline__ float hlo(unsigned u) {
  return __half2float(__ushort_as_half((unsigned short)(u & 0xffffu)));
}
__device__ __forceinline__ float hhi(unsigned u) {
  return __half2float(__ushort_as_half((unsigned short)(u >> 16)));
}

// ---------------------------------------------------------------------------
// prep (1190 blocks): idxv, mstart, masked w_masklin, fp16 uint4-packed GRU
// weights wQ, and fp16 conversions of x (xh) and w_ih (wihh) for the MFMA xp.
// ---------------------------------------------------------------------------
__global__ __launch_bounds__(256) void prep_kernel(
    const int* __restrict__ mask, int* __restrict__ idxv,
    const int* __restrict__ seg, int* __restrict__ mstart,
    fp w_masklin, fp ddi, float* __restrict__ mw,
    fp whh_c, fp whh_p, uint4* __restrict__ wQ,
    fp x_c, fp x_p, __half* __restrict__ xh,
    fp wih_c, fp wih_p, __half* __restrict__ wihh)
{
  int bx = blockIdx.x, tid = threadIdx.x;
  if (bx == 0) {                         // idx[b] = clamp(sum(mask[b,:]) - 1)
    int s = 0;
    const int* mrow = mask + tid * SS;
    for (int t = 0; t < SS; ++t) s += mrow[t];
    s -= 1;
    if (s < 0) s = 0;
    if (s > SS - 1) s = SS - 1;
    idxv[tid] = s;
  } else if (bx == 1) {                  // mstart[m] = lower_bound(seg, m)
    for (int m = tid; m <= NMOL_N; m += 256) {
      if (m == NMOL_N) { mstart[m] = NATOMS_N; continue; }
      int lo = 0, hi = NATOMS_N;
      while (lo < hi) {
        int mid = (lo + hi) >> 1;
        if (seg[mid] < m) lo = mid + 1; else hi = mid;
      }
      mstart[m] = lo;
    }
  } else if (bx < 6) {                   // mw[s][l] = w_masklin[s][l]*ddi[l][s]
    for (int o = (bx - 2) * 256 + tid; o < NSUBS * LBL; o += 4 * 256) {
      int s = o / LBL, l = o - s * LBL;
      mw[o] = w_masklin[o] * ddi[l * NSUBS + s];
    }
  } else if (bx < 70) {                  // weight pack: one (g, kk8) per block
    int lin = bx - 6;                    // 0..63
    int g = lin >> 5;
    int kk8 = lin & 31;
    fp whh = g ? whh_p : whh_c;
    uint4* dst = wQ + (size_t)(g * 32 + kk8) * 768;
#pragma unroll
    for (int gate = 0; gate < 3; ++gate) {
      const float* src = whh + (size_t)(gate * 256 + tid) * HH + kk8 * 8;
      unsigned v0 = __half_as_ushort(__float2half(src[0]));
      unsigned v1 = __half_as_ushort(__float2half(src[1]));
      unsigned v2 = __half_as_ushort(__float2half(src[2]));
      unsigned v3 = __half_as_ushort(__float2half(src[3]));
      unsigned v4 = __half_as_ushort(__float2half(src[4]));
      unsigned v5 = __half_as_ushort(__float2half(src[5]));
      unsigned v6 = __half_as_ushort(__float2half(src[6]));
      unsigned v7 = __half_as_ushort(__float2half(src[7]));
      uint4 u;
      u.x = v0 | (v1 << 16);
      u.y = v2 | (v3 << 16);
      u.z = v4 | (v5 << 16);
      u.w = v6 | (v7 << 16);
      dst[gate * 256 + tid] = u;
    }
  } else if (bx < 1094) {                // x -> fp16 (2 x 1048576 elements)
    int base = (bx - 70) * 2048;
    for (int o = base + tid; o < base + 2048; o += 256) {
      float v = (o < 1048576) ? x_c[o] : x_p[o - 1048576];
      xh[o] = __float2half(v);
    }
  } else {                               // w_ih -> fp16 (2 x 98304 elements)
    int base = (bx - 1094) * 2048;
    for (int o = base + tid; o < base + 2048; o += 256) {
      float v = (o < 98304) ? wih_c[o] : wih_p[o - 98304];
      wihh[o] = __float2half(v);
    }
  }
}

// ---------------------------------------------------------------------------
// xp = x @ w_ih.T + b_ih via fp16 MFMA (fp32 accumulate), stored FP32 so the
// GRU path is bit-compatible with the proven round-13 kernel.
// One 16x16 tile per wave, K=128 in 4 MFMAs. grid (6144, 2) x 256.
// ---------------------------------------------------------------------------
__global__ __launch_bounds__(256) void xp_mfma(
    const __half* __restrict__ xh, const __half* __restrict__ wihh,
    fp bih_c, fp bih_p, float* __restrict__ xp)
{
  int g = blockIdx.y;
  const _Float16* x = (const _Float16*)xh + (size_t)g * 8192 * II;
  const _Float16* wih = (const _Float16*)wihh + (size_t)g * 768 * II;
  fp bih = g ? bih_p : bih_c;
  float* xpo = xp + (size_t)g * 8192 * 768;

  int wave = blockIdx.x * 4 + (threadIdx.x >> 6);
  int lane = threadIdx.x & 63;
  int mt = wave / 48, nt = wave - mt * 48;   // 512 x 48 tiles
  int m0 = mt << 4, n0 = nt << 4;
  int lm = lane & 15, q = lane >> 4;

  const f16x8* ap = (const f16x8*)(x + (size_t)(m0 + lm) * II + q * 8);
  const f16x8* bp = (const f16x8*)(wih + (size_t)(n0 + lm) * II + q * 8);
  f32x4 acc = {0.f, 0.f, 0.f, 0.f};
#pragma unroll
  for (int kk = 0; kk < 4; ++kk)
    acc = __builtin_amdgcn_mfma_f32_16x16x32_f16(ap[kk * 4], bp[kk * 4], acc,
                                                 0, 0, 0);
  float bias = bih[n0 + lm];
#pragma unroll
  for (int r = 0; r < 4; ++r)
    xpo[(size_t)(m0 + q * 4 + r) * 768 + n0 + lm] = acc[r] + bias;
}

// ---------------------------------------------------------------------------
// fully-fused MPNN: one block per molecule (<=14 atoms).
// ---------------------------------------------------------------------------
__global__ __launch_bounds__(256) void mpnn_mol(
    const int* __restrict__ fingerprints, fp embed_fp, fp adj,
    const int* __restrict__ mstart, fp w_g0, fp b_g0, fp w_g1, fp b_g1,
    float* __restrict__ mol)
{
  int m = blockIdx.x, tid = threadIdx.x;
  int a0 = mstart[m], a1 = mstart[m + 1];
  int sz = a1 - a0;
  if (sz < 0) sz = 0;
  if (sz > 14) sz = 14;

  __shared__ float v[14][260];
  __shared__ float adjb[14][16];

#pragma unroll
  for (int i = 0; i < 14; ++i) {
    float val = 0.f;
    if (i < sz) {
      int f = fingerprints[a0 + i] & 1023;
      val = embed_fp[(size_t)f * HH + tid];
    }
    v[i][tid] = val;
  }
  if (tid < 224) {
    int i = tid >> 4, jj = tid & 15;
    float a = 0.f;
    if (i < sz && jj < sz)
      a = adj[(size_t)(a0 + i) * NATOMS_N + a0 + jj];
    adjb[i][jj] = a;
  }
  __syncthreads();

  float acc[14];
  for (int rd = 0; rd < 2; ++rd) {
    const float* wp0 = (rd ? w_g1 : w_g0) + tid;
#pragma unroll
    for (int i = 0; i < 14; ++i) acc[i] = 0.f;
    for (int k = 0; k < HH; k += 4) {
      float w0 = wp0[(size_t)k * HH];
      float w1 = wp0[(size_t)(k + 1) * HH];
      float w2 = wp0[(size_t)(k + 2) * HH];
      float w3 = wp0[(size_t)(k + 3) * HH];
#pragma unroll
      for (int i = 0; i < 14; ++i) {
        float4 vv = *(const float4*)&v[i][k];
        acc[i] = fmaf(vv.x, w0, acc[i]);
        acc[i] = fmaf(vv.y, w1, acc[i]);
        acc[i] = fmaf(vv.z, w2, acc[i]);
        acc[i] = fmaf(vv.w, w3, acc[i]);
      }
    }
    float bias = (rd ? b_g1 : b_g0)[tid];
    float hreg[14];
#pragma unroll
    for (int i = 0; i < 14; ++i) hreg[i] = fmaxf(acc[i] + bias, 0.f);
#pragma unroll
    for (int i = 0; i < 14; ++i) {
      float s = hreg[i];
#pragma unroll
      for (int jj = 0; jj < 14; ++jj) s = fmaf(adjb[i][jj], hreg[jj], s);
      acc[i] = s;
    }
    if (rd == 0) {
      __syncthreads();
#pragma unroll
      for (int i = 0; i < 14; ++i) v[i][tid] = acc[i];
      __syncthreads();
    }
  }
  float msum = 0.f;
#pragma unroll
  for (int i = 0; i < 14; ++i) if (i < sz) msum += acc[i];
  mol[(size_t)m * HH + tid] = msum;
}

// ---------------------------------------------------------------------------
// mpnn_emb^T[h][d] = sum_m avg[d][m] * mol[m][h]
// ---------------------------------------------------------------------------
__global__ __launch_bounds__(256) void mpnn_emb_k(
    fp avg, const float* __restrict__ mol, float* __restrict__ embT)
{
  int d = blockIdx.x, tid = threadIdx.x;
  float acc = 0.f;
  for (int m = 0; m < NMOL_N; ++m)
    acc += avg[d * NMOL_N + m] * mol[(size_t)m * HH + tid];
  embT[(size_t)tid * LBL + d] = acc;
}

// ---------------------------------------------------------------------------
// GRU v4 (round-13 proven): k-split, 256 blocks (g x 128 pairs) x 512 thr.
// fp32 h in LDS; fp16 uint4 weights streamed from XCD-L2; partials via LDS.
// ---------------------------------------------------------------------------
__global__ __launch_bounds__(512) void gru_ks(
    fp xp, const uint4* __restrict__ wQ, fp bhh_c, fp bhh_p,
    float* __restrict__ hcat, const int* __restrict__ idxv)
{
  int blk = blockIdx.x;
  int g = blk >> 7;
  int pair = blk & 127;
  int b1 = pair * 2, b2 = b1 + 1;
  int tid = threadIdx.x;
  int j = tid & 255;
  int kh = tid >> 8;                   // k-half 0/1

  __shared__ float hs[2][260];         // [batch][k]
  __shared__ float red[12][260];       // [kh*6 + batch*3 + gate][j]

  const uint4* wg = wQ + (size_t)(g * 32 + kh * 16) * 768 + j;
  fp bhh = g ? bhh_p : bhh_c;
  const float* xpg = xp + (size_t)g * 8192 * 768;

  if (kh == 0) { hs[0][j] = 0.f; hs[1][j] = 0.f; }
  float br = bhh[j], bz = bhh[j + 256], bn = bhh[j + 512];
  int myb = kh ? b2 : b1;
  int myid = idxv[myb];
  __syncthreads();

  for (int t = 0; t < SS; ++t) {
    const float* h1p = &hs[0][kh * 128];
    const float* h2p = &hs[1][kh * 128];
    float s1r = 0.f, s1z = 0.f, s1n = 0.f;
    float s2r = 0.f, s2z = 0.f, s2n = 0.f;
#pragma unroll 4
    for (int i = 0; i < 16; ++i) {
      float4 a1a = *(const float4*)(h1p + i * 8);
      float4 a1b = *(const float4*)(h1p + i * 8 + 4);
      float4 a2a = *(const float4*)(h2p + i * 8);
      float4 a2b = *(const float4*)(h2p + i * 8 + 4);
      const uint4* base = wg + (size_t)i * 768;
      uint4 ur = base[0];
      uint4 uz = base[256];
      uint4 un = base[512];
      // gate r
      {
        float w0 = hlo(ur.x), w1 = hhi(ur.x), w2 = hlo(ur.y), w3 = hhi(ur.y);
        float w4 = hlo(ur.z), w5 = hhi(ur.z), w6 = hlo(ur.w), w7 = hhi(ur.w);
        s1r = fmaf(a1a.x, w0, s1r); s1r = fmaf(a1a.y, w1, s1r);
        s1r = fmaf(a1a.z, w2, s1r); s1r = fmaf(a1a.w, w3, s1r);
        s1r = fmaf(a1b.x, w4, s1r); s1r = fmaf(a1b.y, w5, s1r);
        s1r = fmaf(a1b.z, w6, s1r); s1r = fmaf(a1b.w, w7, s1r);
        s2r = fmaf(a2a.x, w0, s2r); s2r = fmaf(a2a.y, w1, s2r);
        s2r = fmaf(a2a.z, w2, s2r); s2r = fmaf(a2a.w, w3, s2r);
        s2r = fmaf(a2b.x, w4, s2r); s2r = fmaf(a2b.y, w5, s2r);
        s2r = fmaf(a2b.z, w6, s2r); s2r = fmaf(a2b.w, w7, s2r);
      }
      // gate z
      {
        float w0 = hlo(uz.x), w1 = hhi(uz.x), w2 = hlo(uz.y), w3 = hhi(uz.y);
        float w4 = hlo(uz.z), w5 = hhi(uz.z), w6 = hlo(uz.w), w7 = hhi(uz.w);
        s1z = fmaf(a1a.x, w0, s1z); s1z = fmaf(a1a.y, w1, s1z);
        s1z = fmaf(a1a.z, w2, s1z); s1z = fmaf(a1a.w, w3, s1z);
        s1z = fmaf(a1b.x, w4, s1z); s1z = fmaf(a1b.y, w5, s1z);
        s1z = fmaf(a1b.z, w6, s1z); s1z = fmaf(a1b.w, w7, s1z);
        s2z = fmaf(a2a.x, w0, s2z); s2z = fmaf(a2a.y, w1, s2z);
        s2z = fmaf(a2a.z, w2, s2z); s2z = fmaf(a2a.w, w3, s2z);
        s2z = fmaf(a2b.x, w4, s2z); s2z = fmaf(a2b.y, w5, s2z);
        s2z = fmaf(a2b.z, w6, s2z); s2z = fmaf(a2b.w, w7, s2z);
      }
      // gate n
      {
        float w0 = hlo(un.x), w1 = hhi(un.x), w2 = hlo(un.y), w3 = hhi(un.y);
        float w4 = hlo(un.z), w5 = hhi(un.z), w6 = hlo(un.w), w7 = hhi(un.w);
        s1n = fmaf(a1a.x, w0, s1n); s1n = fmaf(a1a.y, w1, s1n);
        s1n = fmaf(a1a.z, w2, s1n); s1n = fmaf(a1a.w, w3, s1n);
        s1n = fmaf(a1b.x, w4, s1n); s1n = fmaf(a1b.y, w5, s1n);
        s1n = fmaf(a1b.z, w6, s1n); s1n = fmaf(a1b.w, w7, s1n);
        s2n = fmaf(a2a.x, w0, s2n); s2n = fmaf(a2a.y, w1, s2n);
        s2n = fmaf(a2a.z, w2, s2n); s2n = fmaf(a2a.w, w3, s2n);
        s2n = fmaf(a2b.x, w4, s2n); s2n = fmaf(a2b.y, w5, s2n);
        s2n = fmaf(a2b.z, w6, s2n); s2n = fmaf(a2b.w, w7, s2n);
      }
    }
    int rb = kh * 6;
    red[rb + 0][j] = s1r; red[rb + 1][j] = s1z; red[rb + 2][j] = s1n;
    red[rb + 3][j] = s2r; red[rb + 4][j] = s2z; red[rb + 5][j] = s2n;
    __syncthreads();                   // partials visible; all hs reads done

    // gate phase: thread (kh = batch-in-pair, j); writes only its own hs slot
    {
      int bb = kh * 3;
      float sr = red[bb + 0][j] + red[6 + bb + 0][j];
      float sz = red[bb + 1][j] + red[6 + bb + 1][j];
      float sn = red[bb + 2][j] + red[6 + bb + 2][j];
      const float* xrow = xpg + ((size_t)myb * SS + t) * 768;
      float r = sigm(xrow[j] + sr + br);
      float z = sigm(xrow[j + 256] + sz + bz);
      float n = tanhf(xrow[j + 512] + r * (sn + bn));
      float hnew = (1.f - z) * n + z * hs[kh][j];
      hs[kh][j] = hnew;
      if (t == myid) hcat[(size_t)myb * 512 + g * 256 + j] = fmaxf(hnew, 0.f);
    }
    __syncthreads();                   // hs update visible before next step
  }
}

// ---------------------------------------------------------------------------
// fp32 GEMM for query: C[M,N] = A[M,K] @ W[K,N] + bias
// ---------------------------------------------------------------------------
__global__ __launch_bounds__(256) void gemm_f32(
    const float* __restrict__ A, fp W, fp bias, float* __restrict__ C,
    int M, int N, int K)
{
  int ntiles = N >> 4;
  int mt = blockIdx.x / ntiles, nt = blockIdx.x - mt * ntiles;
  int m0 = mt << 4, n0 = nt << 4;
  int tid = threadIdx.x;
  int ni = tid & 15, mi = tid >> 4;
  __shared__ float As[16][68];
  float acc = 0.f;
  for (int k0 = 0; k0 < K; k0 += 64) {
    __syncthreads();
    for (int i = tid; i < 1024; i += 256) {
      int r = i >> 6, kk = i & 63;
      As[r][kk] = A[(size_t)(m0 + r) * K + k0 + kk];
    }
    __syncthreads();
    const float* wp = W + (size_t)k0 * N + n0 + ni;
#pragma unroll 4
    for (int kk = 0; kk < 64; ++kk)
      acc = fmaf(As[mi][kk], wp[(size_t)kk * N], acc);
  }
  acc += bias[n0 + ni];
  C[(size_t)(m0 + mi) * N + n0 + ni] = acc;
}

// ---------------------------------------------------------------------------
// fused tail per batch row: match/x2/LN (mpnn_att) + bip/masked-linear + mul
// ---------------------------------------------------------------------------
__global__ __launch_bounds__(256) void tail_fused(
    const float* __restrict__ query, const float* __restrict__ embT,
    fp w_out, fp b_out, fp gamma, fp beta,
    fp w_bip, fp b_bip, const float* __restrict__ mw,
    float* __restrict__ out)
{
  int b = blockIdx.x, tid = threadIdx.x;
  __shared__ float q[HH];
  __shared__ float mrow[LBL];
  __shared__ float bips[NSUBS];
  __shared__ float red[256];
  q[tid] = query[(size_t)b * HH + tid];
  __syncthreads();
  if (tid < LBL) {
    float acc = 0.f;
    for (int k = 0; k < HH; ++k) acc += q[k] * embT[(size_t)k * LBL + tid];
    mrow[tid] = sigm(acc);
  }
  for (int s = tid; s < NSUBS; s += 256) {
    float acc = b_bip[s];
    for (int k = 0; k < HH; ++k) acc += q[k] * w_bip[(size_t)k * NSUBS + s];
    bips[s] = acc;
  }
  __syncthreads();
  float x2 = 0.f;
  if (tid < LBL) {
    float acc = b_out[tid] + mrow[tid];
    for (int jj = 0; jj < LBL; ++jj) acc += mrow[jj] * w_out[jj * LBL + tid];
    x2 = acc;
  }
  red[tid] = (tid < LBL) ? x2 : 0.f;
  __syncthreads();
  for (int s = 128; s > 0; s >>= 1) {
    if (tid < s) red[tid] += red[tid + s];
    __syncthreads();
  }
  float mu = red[0] / (float)LBL;
  __syncthreads();
  float dv = (tid < LBL) ? (x2 - mu) : 0.f;
  red[tid] = dv * dv;
  __syncthreads();
  for (int s = 128; s > 0; s >>= 1) {
    if (tid < s) red[tid] += red[tid + s];
    __syncthreads();
  }
  float var = red[0] / (float)LBL;
  if (tid < LBL) {
    float matt = (x2 - mu) * rsqrtf(var + 1e-5f) * gamma[tid] + beta[tid];
    float acc = 0.f;
    for (int s = 0; s < NSUBS; ++s) acc += bips[s] * mw[(size_t)s * LBL + tid];
    out[(size_t)b * LBL + tid] = acc * matt;
  }
}

// ---------------------------------------------------------------------------
extern "C" void kernel_launch(void* const* d_in, const int* in_sizes, int n_in,
                              void* d_out, int out_size, void* d_ws, size_t ws_size,
                              hipStream_t stream)
{
  fp x_c   = (fp)d_in[0];
  fp x_p   = (fp)d_in[1];
  const int* mask = (const int*)d_in[2];
  fp wih_c = (fp)d_in[3];
  fp whh_c = (fp)d_in[4];
  fp bih_c = (fp)d_in[5];
  fp bhh_c = (fp)d_in[6];
  fp wih_p = (fp)d_in[7];
  fp whh_p = (fp)d_in[8];
  fp bih_p = (fp)d_in[9];
  fp bhh_p = (fp)d_in[10];
  fp w_query = (fp)d_in[11];
  fp b_query = (fp)d_in[12];
  fp w_bip = (fp)d_in[13];
  fp b_bip = (fp)d_in[14];
  fp w_masklin = (fp)d_in[15];
  fp ddi = (fp)d_in[16];
  fp embed_fp = (fp)d_in[17];
  const int* fingerprints = (const int*)d_in[18];
  fp adj = (fp)d_in[19];
  const int* seg = (const int*)d_in[20];
  fp w_g0 = (fp)d_in[21];
  fp b_g0 = (fp)d_in[22];
  fp w_g1 = (fp)d_in[23];
  fp b_g1 = (fp)d_in[24];
  fp avg = (fp)d_in[25];
  fp w_out = (fp)d_in[26];
  fp b_out = (fp)d_in[27];
  fp gamma = (fp)d_in[28];
  fp beta = (fp)d_in[29];
  float* out = (float*)d_out;

  char* w = (char*)d_ws;
  size_t off = 0;
  auto alloc = [&](size_t bytes) -> void* {
    void* p = w + off;
    off = (off + bytes + 255) & ~(size_t)255;
    return p;
  };

  float* xp   = (float*)alloc((size_t)2 * 8192 * 768 * 4);   // 50.3 MB
  __half* xh  = (__half*)alloc((size_t)2 * 8192 * 128 * 2);  // 4.2 MB
  __half* wihh = (__half*)alloc((size_t)2 * 768 * 128 * 2);  // 0.4 MB
  uint4* wQ   = (uint4*)alloc((size_t)2 * 32 * 768 * 16);    // 786 KB
  float* mol  = (float*)alloc((size_t)NMOL_N * HH * 4);
  float* embT = (float*)alloc((size_t)HH * LBL * 4);
  float* hcat = (float*)alloc((size_t)BB * 2 * HH * 4);
  float* query = (float*)alloc((size_t)BB * HH * 4);
  float* mw   = (float*)alloc((size_t)NSUBS * LBL * 4);
  int* idxv   = (int*)alloc(256 * 4);
  int* mstart = (int*)alloc((NMOL_N + 1) * 4);

  prep_kernel<<<1190, 256, 0, stream>>>(mask, idxv, seg, mstart, w_masklin,
                                        ddi, mw, whh_c, whh_p, wQ,
                                        x_c, x_p, xh, wih_c, wih_p, wihh);

  xp_mfma<<<dim3(6144, 2), 256, 0, stream>>>(xh, wihh, bih_c, bih_p, xp);

  mpnn_mol<<<NMOL_N, 256, 0, stream>>>(fingerprints, embed_fp, adj, mstart,
                                       w_g0, b_g0, w_g1, b_g1, mol);
  mpnn_emb_k<<<LBL, 256, 0, stream>>>(avg, mol, embT);

  gru_ks<<<256, 512, 0, stream>>>(xp, wQ, bhh_c, bhh_p, hcat, idxv);

  gemm_f32<<<256, 256, 0, stream>>>(hcat, w_query, b_query, query, BB, HH, 2 * HH);
  tail_fused<<<BB, 256, 0, stream>>>(query, embT, w_out, b_out, gamma, beta,
                                     w_bip, b_bip, mw, out);
}